// Round 17
// baseline (587.927 us; speedup 1.0000x reference)
//
#include <hip/hip_runtime.h>
#include <stdint.h>

typedef unsigned short u16;
typedef u16 u16x4 __attribute__((ext_vector_type(4)));
typedef u16 u16x8 __attribute__((ext_vector_type(8)));
typedef __bf16 bf16x8 __attribute__((ext_vector_type(8)));
typedef float f32x4 __attribute__((ext_vector_type(4)));
typedef float f32x16 __attribute__((ext_vector_type(16)));

#define MFMA16 __builtin_amdgcn_mfma_f32_16x16x32_bf16
#define MFMA32 __builtin_amdgcn_mfma_f32_32x32x16_bf16

static __device__ __forceinline__ float b2f(u16 u) {
    union { unsigned int i; float f; } v; v.i = ((unsigned int)u) << 16; return v.f;
}
static __device__ __forceinline__ u16 f2b(float f) {
    union { float f; unsigned int i; } v; v.f = f;
    unsigned int r = (v.i + 0x7fffu + ((v.i >> 16) & 1u)) >> 16;
    return (u16)r;
}
static __device__ __forceinline__ unsigned pk2(float lo, float hi) {
    union { __bf16 b[2]; unsigned u; } t;
    t.b[0] = (__bf16)lo; t.b[1] = (__bf16)hi; return t.u;
}
static __device__ __forceinline__ void gload_lds16(const void* g, void* l) {
    __builtin_amdgcn_global_load_lds((__attribute__((address_space(1))) void*)g,
                                     (__attribute__((address_space(3))) void*)l,
                                     16, 0, 0);
}

#define MNQ 8388608L  // 4096*2048 partial size (elements)

// ---------------- fp32 -> bf16 conversion of all 4 weights (one launch) ------
__global__ __launch_bounds__(256) void cvt4_k(const float* __restrict__ s0,
                                              const float* __restrict__ s1,
                                              const float* __restrict__ s2,
                                              const float* __restrict__ s3,
                                              u16* __restrict__ out) {
    long i = ((long)blockIdx.x * 256 + threadIdx.x) * 4;  // < 50331648
    const float* src; long off;
    if (i < 12582912)      { src = s0; off = i; }
    else if (i < 16777216) { src = s1; off = i - 12582912; }
    else if (i < 33554432) { src = s2; off = i - 16777216; }
    else                   { src = s3; off = i - 33554432; }
    float4 v = *(const float4*)(src + off);
    u16x4 o; o[0] = f2b(v.x); o[1] = f2b(v.y); o[2] = f2b(v.z); o[3] = f2b(v.w);
    *(u16x4*)(out + i) = o;
}

// ---- 4-way bf16-partial reduce: xout += sum_k b2f(p[k*MN + i]) --------------
__global__ __launch_bounds__(256) void addred4b_k(float* __restrict__ xout,
                                                  const u16* __restrict__ p) {
    long i = ((long)blockIdx.x * 256 + threadIdx.x) * 4;
    float4 a = *(const float4*)(xout + i);
    #pragma unroll
    for (int k = 0; k < 4; ++k) {
        u16x4 v = *(const u16x4*)(p + k * MNQ + i);
        a.x += b2f(v[0]); a.y += b2f(v[1]); a.z += b2f(v[2]); a.w += b2f(v[3]);
    }
    *(float4*)(xout + i) = a;
}

// ---- fused: xout = x + 4 bf16 partials (p + k*MN); h = rmsnorm(xout)*g ------
// outh MAY alias partial 0 per-element (all reads of an element precede the
// single write of that element within the owning thread).
__global__ __launch_bounds__(256) void addrednorm4b_k(float* __restrict__ xout,
                                                      const float* __restrict__ x,
                                                      const u16* p,
                                                      const float* __restrict__ g,
                                                      u16* outh) {
    const long row = blockIdx.x;
    const int tid = threadIdx.x;
    const long base = row * 2048;
    const long i0 = base + tid * 4;
    const long i1 = base + 1024 + tid * 4;
    float4 a = *(const float4*)(x + i0);
    float4 a2 = *(const float4*)(x + i1);
    #pragma unroll
    for (int k = 0; k < 4; ++k) {
        u16x4 v = *(const u16x4*)(p + k * MNQ + i0);
        a.x += b2f(v[0]); a.y += b2f(v[1]); a.z += b2f(v[2]); a.w += b2f(v[3]);
        u16x4 v2 = *(const u16x4*)(p + k * MNQ + i1);
        a2.x += b2f(v2[0]); a2.y += b2f(v2[1]);
        a2.z += b2f(v2[2]); a2.w += b2f(v2[3]);
    }
    *(float4*)(xout + i0) = a;
    *(float4*)(xout + i1) = a2;
    float ss = a.x*a.x + a.y*a.y + a.z*a.z + a.w*a.w
             + a2.x*a2.x + a2.y*a2.y + a2.z*a2.z + a2.w*a2.w;
    #pragma unroll
    for (int d = 1; d < 64; d <<= 1) ss += __shfl_xor(ss, d);
    __shared__ float red[4];
    if ((tid & 63) == 0) red[tid >> 6] = ss;
    __syncthreads();
    float tot = red[0] + red[1] + red[2] + red[3];
    float rinv = rsqrtf(tot * (1.0f / 2048.0f) + 1e-6f);
    float4 g0 = *(const float4*)(g + tid * 4);
    float4 g1 = *(const float4*)(g + 1024 + tid * 4);
    u16x4 o0, o1;
    o0[0] = f2b(a.x * g0.x * rinv); o0[1] = f2b(a.y * g0.y * rinv);
    o0[2] = f2b(a.z * g0.z * rinv); o0[3] = f2b(a.w * g0.w * rinv);
    o1[0] = f2b(a2.x * g1.x * rinv); o1[1] = f2b(a2.y * g1.y * rinv);
    o1[2] = f2b(a2.z * g1.z * rinv); o1[3] = f2b(a2.w * g1.w * rinv);
    *(u16x4*)(outh + i0) = o0;
    *(u16x4*)(outh + i1) = o1;
}

// ---------------- RMSNorm: fp32 in -> bf16 out (D=2048) ----------------------
__global__ __launch_bounds__(256) void rmsnorm_k(const float* __restrict__ x,
                                                 const float* __restrict__ g,
                                                 u16* __restrict__ out) {
    const long row = blockIdx.x;
    const int tid = threadIdx.x;
    const float* xr = x + row * 2048;
    float4 a = *(const float4*)(xr + tid * 4);
    float4 b = *(const float4*)(xr + 1024 + tid * 4);
    float ss = a.x*a.x + a.y*a.y + a.z*a.z + a.w*a.w
             + b.x*b.x + b.y*b.y + b.z*b.z + b.w*b.w;
    #pragma unroll
    for (int d = 1; d < 64; d <<= 1) ss += __shfl_xor(ss, d);
    __shared__ float red[4];
    if ((tid & 63) == 0) red[tid >> 6] = ss;
    __syncthreads();
    float tot = red[0] + red[1] + red[2] + red[3];
    float rinv = rsqrtf(tot * (1.0f / 2048.0f) + 1e-6f);
    float4 g0 = *(const float4*)(g + tid * 4);
    float4 g1 = *(const float4*)(g + 1024 + tid * 4);
    u16x4 o0, o1;
    o0[0] = f2b(a.x * g0.x * rinv); o0[1] = f2b(a.y * g0.y * rinv);
    o0[2] = f2b(a.z * g0.z * rinv); o0[3] = f2b(a.w * g0.w * rinv);
    o1[0] = f2b(b.x * g1.x * rinv); o1[1] = f2b(b.y * g1.y * rinv);
    o1[2] = f2b(b.z * g1.z * rinv); o1[3] = f2b(b.w * g1.w * rinv);
    *(u16x4*)(out + row * 2048 + tid * 4) = o0;
    *(u16x4*)(out + row * 2048 + 1024 + tid * 4) = o1;
}

// ---------------- RoPE in-place on bf16 qkv (q,k only); q pre-scaled ---------
__global__ __launch_bounds__(256) void rope_k(u16* __restrict__ qkv,
                                              const float* __restrict__ cosb,
                                              const float* __restrict__ sinb) {
    long idx = (long)blockIdx.x * 256 + threadIdx.x;
    int d = (int)(idx & 15) * 4;
    int h = (int)((idx >> 4) & 15);
    int which = (int)((idx >> 8) & 1);
    long row = idx >> 9;
    int s = (int)(row & 2047);
    u16* base = qkv + row * 6144 + which * 2048 + h * 128;
    u16x4 ua = *(u16x4*)(base + d);
    u16x4 ub = *(u16x4*)(base + d + 64);
    float4 c4 = *(const float4*)(cosb + (long)s * 128 + d);
    float4 s4 = *(const float4*)(sinb + (long)s * 128 + d);
    float cc[4] = {c4.x, c4.y, c4.z, c4.w};
    float sn[4] = {s4.x, s4.y, s4.z, s4.w};
    float scale = (which == 0) ? 0.08838834764831845f : 1.0f;
    u16x4 oa, ob;
    #pragma unroll
    for (int j = 0; j < 4; ++j) {
        float a = b2f(ua[j]), b = b2f(ub[j]);
        oa[j] = f2b((a * cc[j] - b * sn[j]) * scale);
        ob[j] = f2b((b * cc[j] + a * sn[j]) * scale);
    }
    *(u16x4*)(base + d) = oa;
    *(u16x4*)(base + d + 64) = ob;
}

// ---------------- GEMM 256x256, BK=32 / 4-phase / 64KB LDS -------------------
// r14 structure (reg-fragment double-buffer, setprio on MFMA).
// EPI: 0 bf16; 1 fp32+res; 2 gelu bf16; 4 bf16 + v-transpose; 6 bf16 PARTIAL
// (ksplit=4) at pq + kseg*M*N.
#define DS_A(BUF, SM) (*(const bf16x8*)(ldsb + (BUF)*16384 + ((SM) << 10) + rin64 + cst2))
#define DS_B(BUF, SN) (*(const bf16x8*)(ldsb + 32768 + (BUF)*16384 + ((SN) << 10) + rin64 + cst2))
#define STAGE_A(BUF, KT) do { \
    gload_lds16(sA0 + ((long)(KT)*32), ldsb + (BUF)*16384 + (w*2)*1024); \
    gload_lds16(sA1 + ((long)(KT)*32), ldsb + (BUF)*16384 + (w*2+1)*1024); \
} while (0)
#define STAGE_B(BUF, KT) do { \
    gload_lds16(sB0 + ((long)(KT)*32), ldsb + 32768 + (BUF)*16384 + (w*2)*1024); \
    gload_lds16(sB1 + ((long)(KT)*32), ldsb + 32768 + (BUF)*16384 + (w*2+1)*1024); \
} while (0)
#define PREF_A(DST, BUF, MH) do { \
    _Pragma("unroll") \
    for (int m = 0; m < 4; ++m) DST[m] = DS_A(BUF, wr8 + (MH)*4 + m); \
} while (0)
#define PREF_B(DST, BUF) do { \
    _Pragma("unroll") \
    for (int n = 0; n < 4; ++n) DST[n] = DS_B(BUF, wc4 + n); \
} while (0)
#define MFMA_Q(MH, AF, BF) do { \
    __builtin_amdgcn_s_setprio(1); \
    _Pragma("unroll") \
    for (int m = 0; m < 4; ++m) \
        _Pragma("unroll") \
        for (int n = 0; n < 4; ++n) \
            acc[(MH)*4 + m][n] = MFMA16(AF[m], BF[n], acc[(MH)*4 + m][n], 0, 0, 0); \
    __builtin_amdgcn_s_setprio(0); \
} while (0)
#define VMC2 asm volatile("s_waitcnt vmcnt(2)" ::: "memory")
#define BAR  __builtin_amdgcn_s_barrier()

template <int EPI>
__global__ __launch_bounds__(512, 2) void gemm256(const u16* __restrict__ A,
                                                  const u16* __restrict__ W,
                                                  int M, int N, int K,
                                                  u16* outb, float* outf,
                                                  const float* res, u16* vtw,
                                                  u16* pq, int ksplit) {
    __shared__ u16 lds_[32768];
    char* ldsb = (char*)lds_;
    const int tid = threadIdx.x;
    const int w = tid >> 6, l = tid & 63;
    const int wr8 = (w >> 2) * 8;
    const int wc4 = (w & 3) * 4;
    const int rin64 = (l & 15) * 64;
    const int cst2 = ((((l >> 4) * 8) ^ (((l >> 3) & 1) << 4)) << 1);

    const int nbn = N >> 8;
    const int nbm = M >> 8;
    const int nwg = gridDim.x;
    const int cpx = nwg >> 3;
    const int bid = blockIdx.x;
    int wg = (bid & 7) * cpx + (bid >> 3);
    int kseg = 0;
    int Keff = K;
    if (ksplit == 4) {
        kseg = wg & 3;
        wg >>= 2;
        Keff = K >> 2;
    }
    const int grp = 8 * nbn;
    const int g8 = wg / grp;
    const int rem = wg - g8 * grp;
    const int bm0 = g8 * 8;
    const int gmh = (nbm - bm0 < 8) ? (nbm - bm0) : 8;
    const int bn = rem / gmh;
    const int bm = bm0 + rem % gmh;
    const u16* Ab = A + (long)kseg * Keff;
    const u16* Wb = W + (long)kseg * Keff;

    const int r4 = l >> 2;
    const int clog = ((l & 3) * 8) ^ (((r4 >> 3) & 1) << 4);
    const u16* sA0 = Ab + ((long)bm * 256 + (w * 2 + 0) * 16 + r4) * K + clog;
    const u16* sA1 = Ab + ((long)bm * 256 + (w * 2 + 1) * 16 + r4) * K + clog;
    const u16* sB0 = Wb + ((long)bn * 256 + (w * 2 + 0) * 16 + r4) * K + clog;
    const u16* sB1 = Wb + ((long)bn * 256 + (w * 2 + 1) * 16 + r4) * K + clog;

    f32x4 acc[8][4];
    #pragma unroll
    for (int m = 0; m < 8; ++m)
        #pragma unroll
        for (int n = 0; n < 4; ++n) acc[m][n] = (f32x4){0.f, 0.f, 0.f, 0.f};
    bf16x8 afc[4], afn[4], bfc[4], bfn[4];

    const int nkt = Keff >> 5;          // K-tiles of 32
    const int niter = nkt >> 1;

    // prologue
    STAGE_A(0, 0); STAGE_B(0, 0); STAGE_A(1, 1); STAGE_B(1, 1);
    asm volatile("s_waitcnt vmcnt(4)" ::: "memory");
    BAR;
    PREF_A(afc, 0, 0); PREF_B(bfc, 0);
    BAR;

    for (int it = 0; it < niter; ++it) {
        const int t = it * 2;
        const int t2 = (t + 2 < nkt) ? t + 2 : nkt - 1;
        const int t3 = (t + 3 < nkt) ? t + 3 : nkt - 1;
        // P1
        PREF_A(afn, 0, 1);
        STAGE_B(0, t2);
        MFMA_Q(0, afc, bfc);
        VMC2;
        BAR;
        // P2
        PREF_A(afc, 1, 0); PREF_B(bfn, 1);
        STAGE_A(0, t2);
        MFMA_Q(1, afn, bfc);
        BAR;
        // P3
        PREF_A(afn, 1, 1);
        STAGE_B(1, t3);
        MFMA_Q(0, afc, bfn);
        VMC2;
        BAR;
        // P4
        PREF_A(afc, 0, 0); PREF_B(bfc, 0);
        STAGE_A(1, t3);
        MFMA_Q(1, afn, bfn);
        BAR;
    }
    asm volatile("s_waitcnt vmcnt(0)" ::: "memory");

    // epilogue
    const int rb = bm * 256 + (wr8 >> 3) * 128 + ((l >> 4) << 2);
    const int cb = bn * 256 + (w & 3) * 64 + (l & 15);
    if (EPI == 4) {
        const bool vreg = (cb >= 4096);
        #pragma unroll
        for (int m = 0; m < 8; ++m) {
            long row0 = rb + m * 16;
            #pragma unroll
            for (int n = 0; n < 4; ++n) {
                long col = cb + n * 16;
                if (vreg) {
                    int d = (int)col & 127;
                    int hh = ((int)col >> 7) - 32;
                    long bh = (row0 >> 11) * 16 + hh;
                    int s = (int)(row0 & 2047);
                    u16x4 o4;
                    #pragma unroll
                    for (int r = 0; r < 4; ++r) o4[r] = f2b(acc[m][n][r]);
                    *(u16x4*)(vtw + (bh * 128 + d) * 2048 + s) = o4;
                } else {
                    #pragma unroll
                    for (int r = 0; r < 4; ++r)
                        outb[(row0 + r) * N + col] = f2b(acc[m][n][r]);
                }
            }
        }
        return;
    }
    if (EPI == 6) {
        u16* pb = pq + (long)kseg * MNQ;
        #pragma unroll
        for (int m = 0; m < 8; ++m) {
            #pragma unroll
            for (int r = 0; r < 4; ++r) {
                long row = rb + m * 16 + r;
                #pragma unroll
                for (int n = 0; n < 4; ++n)
                    pb[row * N + cb + n * 16] = f2b(acc[m][n][r]);
            }
        }
        return;
    }
    #pragma unroll
    for (int m = 0; m < 8; ++m) {
        #pragma unroll
        for (int r = 0; r < 4; ++r) {
            long row = rb + m * 16 + r;
            #pragma unroll
            for (int n = 0; n < 4; ++n) {
                long col = cb + n * 16;
                float v = acc[m][n][r];
                if (EPI == 1) {
                    outf[row * N + col] = res[row * N + col] + v;
                } else if (EPI == 2) {
                    float u = 0.7978845608028654f * v * (1.0f + 0.044715f * v * v);
                    float e = __expf(2.0f * u);
                    float tgl = 1.0f - 2.0f / (e + 1.0f);
                    outb[row * N + col] = f2b(0.5f * v * (1.0f + tgl));
                } else {
                    outb[row * N + col] = f2b(v);
                }
            }
        }
    }
}

// ---------------- causal flash attention v5: 8-wave, 4 q-tiles/block ---------
struct AttnState {
    f32x16 acc[4];
    float m_i, l_i;
};

template <bool DIAG>
static __device__ __forceinline__ void attn_tile(
    int kv0, int qg, bool do_g1, int l31, int hi,
    const u16* __restrict__ Ks, const u16* __restrict__ Vt,
    const bf16x8 (&qf)[8], AttnState& st)
{
    f32x16 sacc0, sacc1;
    #pragma unroll
    for (int r = 0; r < 16; ++r) { sacc0[r] = 0.f; sacc1[r] = 0.f; }

    __builtin_amdgcn_s_setprio(1);
    #pragma unroll
    for (int dsl = 0; dsl < 8; ++dsl) {
        int slot = dsl * 2 + hi;
        int kv = l31;
        int sw = (slot & 8) | ((slot & 7) ^ (kv & 7));
        bf16x8 kf = *(const bf16x8*)(Ks + kv * 128 + sw * 8);
        sacc0 = MFMA32(kf, qf[dsl], sacc0, 0, 0, 0);
    }
    if (do_g1) {
        #pragma unroll
        for (int dsl = 0; dsl < 8; ++dsl) {
            int slot = dsl * 2 + hi;
            int kv = 32 + l31;
            int sw = (slot & 8) | ((slot & 7) ^ (kv & 7));
            bf16x8 kf = *(const bf16x8*)(Ks + kv * 128 + sw * 8);
            sacc1 = MFMA32(kf, qf[dsl], sacc1, 0, 0, 0);
        }
    }
    __builtin_amdgcn_s_setprio(0);

    float sv[2][16];
    #pragma unroll
    for (int r = 0; r < 16; ++r) {
        sv[0][r] = sacc0[r];
        sv[1][r] = do_g1 ? sacc1[r] : -INFINITY;
    }
    if (DIAG) {
        #pragma unroll
        for (int g = 0; g < 2; ++g)
            #pragma unroll
            for (int r = 0; r < 16; ++r) {
                int kvg = kv0 + g * 32 + ((r & 3) + 8 * (r >> 2) + 4 * hi);
                if (kvg > qg) sv[g][r] = -INFINITY;
            }
    }

    float mx = sv[0][0];
    #pragma unroll
    for (int r = 1; r < 16; ++r) mx = fmaxf(mx, sv[0][r]);
    #pragma unroll
    for (int r = 0; r < 16; ++r) mx = fmaxf(mx, sv[1][r]);
    mx = fmaxf(mx, __shfl_xor(mx, 32));

    bool defer = __all(mx <= st.m_i + 8.0f);
    if (!defer) {
        float mnew = fmaxf(st.m_i, mx);
        float f = __expf(st.m_i - mnew);
        st.l_i *= f;
        #pragma unroll
        for (int dblk = 0; dblk < 4; ++dblk)
            #pragma unroll
            for (int r = 0; r < 16; ++r) st.acc[dblk][r] *= f;
        st.m_i = mnew;
    }

    float ssum = 0.f;
    #pragma unroll
    for (int g = 0; g < 2; ++g)
        #pragma unroll
        for (int r = 0; r < 16; ++r) {
            float e = __expf(sv[g][r] - st.m_i);
            sv[g][r] = e;
            ssum += e;
        }
    ssum += __shfl_xor(ssum, 32);
    st.l_i += ssum;

    unsigned w[2][4][2];
    #pragma unroll
    for (int g = 0; g < 2; ++g)
        #pragma unroll
        for (int q4 = 0; q4 < 4; ++q4) {
            w[g][q4][0] = pk2(sv[g][4 * q4 + 0], sv[g][4 * q4 + 1]);
            w[g][q4][1] = pk2(sv[g][4 * q4 + 2], sv[g][4 * q4 + 3]);
        }
    bf16x8 pfrag[4];
    #pragma unroll
    for (int ks = 0; ks < 4; ++ks) {
        int g = ks >> 1, h2 = ks & 1;
        unsigned o0 = hi ? w[g][2 * h2 + 1][0] : w[g][2 * h2][0];
        unsigned o1 = hi ? w[g][2 * h2 + 1][1] : w[g][2 * h2][1];
        unsigned t0 = hi ? w[g][2 * h2][0] : w[g][2 * h2 + 1][0];
        unsigned t1 = hi ? w[g][2 * h2][1] : w[g][2 * h2 + 1][1];
        unsigned s0v = __shfl_xor(t0, 32);
        unsigned s1v = __shfl_xor(t1, 32);
        union { unsigned u[4]; bf16x8 v; } cv;
        cv.u[0] = hi ? s0v : o0;
        cv.u[1] = hi ? s1v : o1;
        cv.u[2] = hi ? o0 : s0v;
        cv.u[3] = hi ? o1 : s1v;
        pfrag[ks] = cv.v;
    }

    __builtin_amdgcn_s_setprio(1);
    #pragma unroll
    for (int dblk = 0; dblk < 4; ++dblk) {
        int d = dblk * 32 + l31;
        #pragma unroll
        for (int ks = 0; ks < 4; ++ks) {
            if (ks >= 2 && !do_g1) continue;
            int slot = ks * 2 + hi;
            bf16x8 vf = *(const bf16x8*)(Vt + d * 64 + (slot ^ (d & 7)) * 8);
            st.acc[dblk] = MFMA32(vf, pfrag[ks], st.acc[dblk], 0, 0, 0);
        }
    }
    __builtin_amdgcn_s_setprio(0);
}

__global__ __launch_bounds__(512) void attn5_k(const u16* __restrict__ qkv,
                                               const u16* __restrict__ vt,
                                               u16* __restrict__ out) {
    const int bh = blockIdx.y;            // 0..31
    const int b = bh >> 4, h = bh & 15;
    const int j = blockIdx.x;             // 0..7
    const int tid = threadIdx.x, wave = tid >> 6, lane = tid & 63;
    const int l31 = lane & 31, hi = lane >> 5;
    const int brow = b * 2048;
    __shared__ u16 Ks_lds[2][64 * 128];
    __shared__ u16 Vt_lds[2][128 * 64];

    const int tsel = wave >> 1;
    const int qt = (tsel == 0) ? j : (tsel == 1) ? (15 - j)
                 : (tsel == 2) ? (16 + j) : (31 - j);
    const int r0 = qt * 64 + (wave & 1) * 32;
    const int qg = r0 + l31;

    bf16x8 qf[8];
    {
        const u16* qp = qkv + (long)(brow + r0 + l31) * 6144 + h * 128 + hi * 8;
        #pragma unroll
        for (int dsl = 0; dsl < 8; ++dsl) qf[dsl] = *(const bf16x8*)(qp + dsl * 16);
    }

    AttnState st;
    st.m_i = -INFINITY; st.l_i = 0.f;
    #pragma unroll
    for (int dblk = 0; dblk < 4; ++dblk)
        #pragma unroll
        for (int r = 0; r < 16; ++r) st.acc[dblk][r] = 0.f;

    const int nt = 32 - j;
    int cur = 0;

    const int krow = tid >> 4;
    const int kslot = tid & 15;
    const int vrow = tid >> 3;
    const int vslot = tid & 7;

#define STAGE_KV(BUF, KV0) do { \
    _Pragma("unroll") \
    for (int i = 0; i < 2; ++i) { \
        int kv = i * 32 + krow; \
        int sw = (kslot & 8) | ((kslot & 7) ^ (kv & 7)); \
        const u16* src = qkv + (long)(brow + (KV0) + kv) * 6144 + 2048 + \
                         h * 128 + sw * 8; \
        gload_lds16(src, (char*)Ks_lds[BUF] + (i * 32 + wave * 4) * 256); \
    } \
    _Pragma("unroll") \
    for (int i = 0; i < 2; ++i) { \
        int d = i * 64 + vrow; \
        int sw = vslot ^ (d & 7); \
        const u16* src = vt + ((long)bh * 128 + d) * 2048 + (KV0) + sw * 8; \
        gload_lds16(src, (char*)Vt_lds[BUF] + (i * 64 + wave * 8) * 128); \
    } \
} while (0)

    STAGE_KV(0, 0);
    for (int t = 0; t < nt; ++t) {
        const int kv0 = t * 64;
        const bool more = (t + 1 < nt);
        if (more) {
            if (cur) STAGE_KV(0, kv0 + 64); else STAGE_KV(1, kv0 + 64);
        }
        if (more) { asm volatile("s_waitcnt vmcnt(4)" ::: "memory"); }
        else      { asm volatile("s_waitcnt vmcnt(0)" ::: "memory"); }
        __builtin_amdgcn_sched_barrier(0);
        __builtin_amdgcn_s_barrier();
        __builtin_amdgcn_sched_barrier(0);
        {
            const u16* Ks = Ks_lds[cur];
            const u16* Vt_ = Vt_lds[cur];
            const int delta = r0 - kv0;
            if (delta >= 64)
                attn_tile<false>(kv0, qg, true, l31, hi, Ks, Vt_, qf, st);
            else if (delta >= 0)
                attn_tile<true>(kv0, qg, delta >= 32, l31, hi, Ks, Vt_, qf, st);
        }
        __builtin_amdgcn_sched_barrier(0);
        __builtin_amdgcn_s_barrier();
        __builtin_amdgcn_sched_barrier(0);
        cur ^= 1;
    }
#undef STAGE_KV

    float inv = 1.0f / st.l_i;
    long orow = (long)(brow + r0 + l31);
    #pragma unroll
    for (int dblk = 0; dblk < 4; ++dblk)
        #pragma unroll
        for (int rq = 0; rq < 4; ++rq) {
            u16x4 o4;
            #pragma unroll
            for (int m = 0; m < 4; ++m) o4[m] = f2b(st.acc[dblk][rq * 4 + m] * inv);
            int d = dblk * 32 + 8 * rq + 4 * hi;
            *(u16x4*)(out + orow * 2048 + h * 128 + d) = o4;
        }
}

// ---------------- launch --------------------------------------------------
extern "C" void kernel_launch(void* const* d_in, const int* in_sizes, int n_in,
                              void* d_out, int out_size, void* d_ws, size_t ws_size,
                              hipStream_t stream) {
    const float* x     = (const float*)d_in[0];
    const float* cosb  = (const float*)d_in[1];
    const float* sinb  = (const float*)d_in[2];
    const float* g1    = (const float*)d_in[3];
    const float* g2    = (const float*)d_in[4];
    const float* w_qkv = (const float*)d_in[5];
    const float* w_out = (const float*)d_in[6];
    const float* w_fc1 = (const float*)d_in[7];
    const float* w_fc2 = (const float*)d_in[8];

    char* ws = (char*)d_ws;
    u16* wqkv_b = (u16*)(ws);                    // 6144x2048 bf16 (0..25.2MB)
    u16* wout_b = (u16*)(ws + 25165824);         // 2048x2048 (25.2..33.6)
    u16* wfc1_b = (u16*)(ws + 33554432);         // 8192x2048 (33.6..67.1)
    u16* wfc2_b = (u16*)(ws + 67108864);         // 2048x8192 (67.1..100.7)
    u16* h_b    = (u16*)(ws + 100663296);        // 4096x2048 bf16 (100.7..117.4)
    u16* qkv_b  = (u16*)(ws + 117440512);        // 4096x6144 (117.4..167.8)
    u16* attn_b = (u16*)(ws + 167772160);        // 4096x2048 (167.8..184.5)
    u16* hg_b   = qkv_b;                         // 4096x8192 (fc1 out)
    u16* vt_b   = (u16*)d_out;                   // 32x128x2048 bf16 (16.7MB);
                                                 // d_out dead until addrednorm4b
    // out-proj bf16 partials: 4 x 16.8MB @ ws+100663296 (h_b..qkv, both dead
    // at out-proj time; ends exactly at attn_b). addrednorm4b's outh = h_b
    // aliases partial 0 per-element (read-then-write within thread).
    u16* pop  = h_b;
    // fc2 bf16 partials: 4 x 16.8MB @ ws+0 (dead wqkv+wout+wfc1 = 67.1MB exact;
    // disjoint from wfc2_b at 67.1.. and input hg at 117.4..)
    u16* pfc2 = (u16*)ws;
    float* xout = (float*)d_out;

    cvt4_k<<<49152, 256, 0, stream>>>(w_qkv, w_out, w_fc1, w_fc2, (u16*)ws);

    rmsnorm_k<<<4096, 256, 0, stream>>>(x, g1, h_b);
    gemm256<4><<<384, 512, 0, stream>>>(h_b, wqkv_b, 4096, 6144, 2048,
                                        qkv_b, nullptr, nullptr, vt_b,
                                        nullptr, 1);
    rope_k<<<8192, 256, 0, stream>>>(qkv_b, cosb, sinb);
    attn5_k<<<dim3(8, 32), 512, 0, stream>>>(qkv_b, vt_b, attn_b);
    // out-proj: 512 blocks (ksplit=4), bf16 partials in dead h_b..qkv region
    gemm256<6><<<512, 512, 0, stream>>>(attn_b, wout_b, 4096, 2048, 2048,
                                        nullptr, nullptr, nullptr, nullptr,
                                        pop, 4);
    addrednorm4b_k<<<4096, 256, 0, stream>>>(xout, x, pop, g2, h_b);
    gemm256<2><<<512, 512, 0, stream>>>(h_b, wfc1_b, 4096, 8192, 2048,
                                        hg_b, nullptr, nullptr, nullptr,
                                        nullptr, 1);
    // fc2: 512 blocks (ksplit=4), bf16 partials over dead weight region
    gemm256<6><<<512, 512, 0, stream>>>(hg_b, wfc2_b, 4096, 2048, 8192,
                                        nullptr, nullptr, nullptr, nullptr,
                                        pfc2, 4);
    addred4b_k<<<8192, 256, 0, stream>>>(xout, pfc2);
}

// Round 18
// 572.254 us; speedup vs baseline: 1.0274x; 1.0274x over previous
//
#include <hip/hip_runtime.h>
#include <stdint.h>

typedef unsigned short u16;
typedef u16 u16x4 __attribute__((ext_vector_type(4)));
typedef u16 u16x8 __attribute__((ext_vector_type(8)));
typedef __bf16 bf16x8 __attribute__((ext_vector_type(8)));
typedef float f32x4 __attribute__((ext_vector_type(4)));
typedef float f32x16 __attribute__((ext_vector_type(16)));

#define MFMA16 __builtin_amdgcn_mfma_f32_16x16x32_bf16
#define MFMA32 __builtin_amdgcn_mfma_f32_32x32x16_bf16

static __device__ __forceinline__ float b2f(u16 u) {
    union { unsigned int i; float f; } v; v.i = ((unsigned int)u) << 16; return v.f;
}
static __device__ __forceinline__ u16 f2b(float f) {
    union { float f; unsigned int i; } v; v.f = f;
    unsigned int r = (v.i + 0x7fffu + ((v.i >> 16) & 1u)) >> 16;
    return (u16)r;
}
static __device__ __forceinline__ unsigned pk2(float lo, float hi) {
    union { __bf16 b[2]; unsigned u; } t;
    t.b[0] = (__bf16)lo; t.b[1] = (__bf16)hi; return t.u;
}
static __device__ __forceinline__ void gload_lds16(const void* g, void* l) {
    __builtin_amdgcn_global_load_lds((__attribute__((address_space(1))) void*)g,
                                     (__attribute__((address_space(3))) void*)l,
                                     16, 0, 0);
}

// ---------------- fp32 -> bf16 conversion of all 4 weights (one launch) ------
__global__ __launch_bounds__(256) void cvt4_k(const float* __restrict__ s0,
                                              const float* __restrict__ s1,
                                              const float* __restrict__ s2,
                                              const float* __restrict__ s3,
                                              u16* __restrict__ out) {
    long i = ((long)blockIdx.x * 256 + threadIdx.x) * 4;  // < 50331648
    const float* src; long off;
    if (i < 12582912)      { src = s0; off = i; }
    else if (i < 16777216) { src = s1; off = i - 12582912; }
    else if (i < 33554432) { src = s2; off = i - 16777216; }
    else                   { src = s3; off = i - 33554432; }
    float4 v = *(const float4*)(src + off);
    u16x4 o; o[0] = f2b(v.x); o[1] = f2b(v.y); o[2] = f2b(v.z); o[3] = f2b(v.w);
    *(u16x4*)(out + i) = o;
}

// ---------------- split-K reduce: xout += p0 + p1 ----------------------------
__global__ __launch_bounds__(256) void addred_k(float* __restrict__ xout,
                                                const float* __restrict__ p0,
                                                const float* __restrict__ p1) {
    long i = ((long)blockIdx.x * 256 + threadIdx.x) * 4;
    float4 a = *(const float4*)(xout + i);
    float4 b = *(const float4*)(p0 + i);
    float4 c = *(const float4*)(p1 + i);
    a.x += b.x + c.x; a.y += b.y + c.y; a.z += b.z + c.z; a.w += b.w + c.w;
    *(float4*)(xout + i) = a;
}

// ---- fused: xout = x + p0 + p1; h = rmsnorm(xout)*g  (xout MAY alias p0) ----
__global__ __launch_bounds__(256) void addrednorm_k(float* xout,
                                                    const float* __restrict__ x,
                                                    const float* p0,
                                                    const float* __restrict__ p1,
                                                    const float* __restrict__ g,
                                                    u16* __restrict__ out) {
    const long row = blockIdx.x;
    const int tid = threadIdx.x;
    const long base = row * 2048;
    float4 a = *(const float4*)(x + base + tid * 4);
    float4 b = *(const float4*)(p0 + base + tid * 4);
    float4 c = *(const float4*)(p1 + base + tid * 4);
    a.x += b.x + c.x; a.y += b.y + c.y; a.z += b.z + c.z; a.w += b.w + c.w;
    float4 a2 = *(const float4*)(x + base + 1024 + tid * 4);
    float4 b2 = *(const float4*)(p0 + base + 1024 + tid * 4);
    float4 c2 = *(const float4*)(p1 + base + 1024 + tid * 4);
    a2.x += b2.x + c2.x; a2.y += b2.y + c2.y;
    a2.z += b2.z + c2.z; a2.w += b2.w + c2.w;
    *(float4*)(xout + base + tid * 4) = a;
    *(float4*)(xout + base + 1024 + tid * 4) = a2;
    float ss = a.x*a.x + a.y*a.y + a.z*a.z + a.w*a.w
             + a2.x*a2.x + a2.y*a2.y + a2.z*a2.z + a2.w*a2.w;
    #pragma unroll
    for (int d = 1; d < 64; d <<= 1) ss += __shfl_xor(ss, d);
    __shared__ float red[4];
    if ((tid & 63) == 0) red[tid >> 6] = ss;
    __syncthreads();
    float tot = red[0] + red[1] + red[2] + red[3];
    float rinv = rsqrtf(tot * (1.0f / 2048.0f) + 1e-6f);
    float4 g0 = *(const float4*)(g + tid * 4);
    float4 g1 = *(const float4*)(g + 1024 + tid * 4);
    u16x4 o0, o1;
    o0[0] = f2b(a.x * g0.x * rinv); o0[1] = f2b(a.y * g0.y * rinv);
    o0[2] = f2b(a.z * g0.z * rinv); o0[3] = f2b(a.w * g0.w * rinv);
    o1[0] = f2b(a2.x * g1.x * rinv); o1[1] = f2b(a2.y * g1.y * rinv);
    o1[2] = f2b(a2.z * g1.z * rinv); o1[3] = f2b(a2.w * g1.w * rinv);
    *(u16x4*)(out + base + tid * 4) = o0;
    *(u16x4*)(out + base + 1024 + tid * 4) = o1;
}

// ---------------- RMSNorm: fp32 in -> bf16 out (D=2048) ----------------------
__global__ __launch_bounds__(256) void rmsnorm_k(const float* __restrict__ x,
                                                 const float* __restrict__ g,
                                                 u16* __restrict__ out) {
    const long row = blockIdx.x;
    const int tid = threadIdx.x;
    const float* xr = x + row * 2048;
    float4 a = *(const float4*)(xr + tid * 4);
    float4 b = *(const float4*)(xr + 1024 + tid * 4);
    float ss = a.x*a.x + a.y*a.y + a.z*a.z + a.w*a.w
             + b.x*b.x + b.y*b.y + b.z*b.z + b.w*b.w;
    #pragma unroll
    for (int d = 1; d < 64; d <<= 1) ss += __shfl_xor(ss, d);
    __shared__ float red[4];
    if ((tid & 63) == 0) red[tid >> 6] = ss;
    __syncthreads();
    float tot = red[0] + red[1] + red[2] + red[3];
    float rinv = rsqrtf(tot * (1.0f / 2048.0f) + 1e-6f);
    float4 g0 = *(const float4*)(g + tid * 4);
    float4 g1 = *(const float4*)(g + 1024 + tid * 4);
    u16x4 o0, o1;
    o0[0] = f2b(a.x * g0.x * rinv); o0[1] = f2b(a.y * g0.y * rinv);
    o0[2] = f2b(a.z * g0.z * rinv); o0[3] = f2b(a.w * g0.w * rinv);
    o1[0] = f2b(b.x * g1.x * rinv); o1[1] = f2b(b.y * g1.y * rinv);
    o1[2] = f2b(b.z * g1.z * rinv); o1[3] = f2b(b.w * g1.w * rinv);
    *(u16x4*)(out + row * 2048 + tid * 4) = o0;
    *(u16x4*)(out + row * 2048 + 1024 + tid * 4) = o1;
}

// ---------------- RoPE in-place on bf16 qkv (q,k only); q pre-scaled ---------
__global__ __launch_bounds__(256) void rope_k(u16* __restrict__ qkv,
                                              const float* __restrict__ cosb,
                                              const float* __restrict__ sinb) {
    long idx = (long)blockIdx.x * 256 + threadIdx.x;
    int d = (int)(idx & 15) * 4;
    int h = (int)((idx >> 4) & 15);
    int which = (int)((idx >> 8) & 1);
    long row = idx >> 9;
    int s = (int)(row & 2047);
    u16* base = qkv + row * 6144 + which * 2048 + h * 128;
    u16x4 ua = *(u16x4*)(base + d);
    u16x4 ub = *(u16x4*)(base + d + 64);
    float4 c4 = *(const float4*)(cosb + (long)s * 128 + d);
    float4 s4 = *(const float4*)(sinb + (long)s * 128 + d);
    float cc[4] = {c4.x, c4.y, c4.z, c4.w};
    float sn[4] = {s4.x, s4.y, s4.z, s4.w};
    float scale = (which == 0) ? 0.08838834764831845f : 1.0f;
    u16x4 oa, ob;
    #pragma unroll
    for (int j = 0; j < 4; ++j) {
        float a = b2f(ua[j]), b = b2f(ub[j]);
        oa[j] = f2b((a * cc[j] - b * sn[j]) * scale);
        ob[j] = f2b((b * cc[j] + a * sn[j]) * scale);
    }
    *(u16x4*)(base + d) = oa;
    *(u16x4*)(base + d + 64) = ob;
}

// ---------------- GEMM 256x256, BK=32 / 4-phase / 64KB LDS -------------------
// 512 thr = 8 waves (2M x 4N). LDS: A[buf]*16K, B at 32K+[buf]*16K; subtiles
// 16x32 st_16x32-swizzled. Register fragment double-buffer: each phase
// prefetches the NEXT phase's fragments before its own MFMA (counted lgkm).
// vmcnt(2) at P1/P3 ends; one barrier per phase. Best measured config (r14).
#define DS_A(BUF, SM) (*(const bf16x8*)(ldsb + (BUF)*16384 + ((SM) << 10) + rin64 + cst2))
#define DS_B(BUF, SN) (*(const bf16x8*)(ldsb + 32768 + (BUF)*16384 + ((SN) << 10) + rin64 + cst2))
#define STAGE_A(BUF, KT) do { \
    gload_lds16(sA0 + ((long)(KT)*32), ldsb + (BUF)*16384 + (w*2)*1024); \
    gload_lds16(sA1 + ((long)(KT)*32), ldsb + (BUF)*16384 + (w*2+1)*1024); \
} while (0)
#define STAGE_B(BUF, KT) do { \
    gload_lds16(sB0 + ((long)(KT)*32), ldsb + 32768 + (BUF)*16384 + (w*2)*1024); \
    gload_lds16(sB1 + ((long)(KT)*32), ldsb + 32768 + (BUF)*16384 + (w*2+1)*1024); \
} while (0)
#define PREF_A(DST, BUF, MH) do { \
    _Pragma("unroll") \
    for (int m = 0; m < 4; ++m) DST[m] = DS_A(BUF, wr8 + (MH)*4 + m); \
} while (0)
#define PREF_B(DST, BUF) do { \
    _Pragma("unroll") \
    for (int n = 0; n < 4; ++n) DST[n] = DS_B(BUF, wc4 + n); \
} while (0)
#define MFMA_Q(MH, AF, BF) do { \
    __builtin_amdgcn_s_setprio(1); \
    _Pragma("unroll") \
    for (int m = 0; m < 4; ++m) \
        _Pragma("unroll") \
        for (int n = 0; n < 4; ++n) \
            acc[(MH)*4 + m][n] = MFMA16(AF[m], BF[n], acc[(MH)*4 + m][n], 0, 0, 0); \
    __builtin_amdgcn_s_setprio(0); \
} while (0)
#define VMC2 asm volatile("s_waitcnt vmcnt(2)" ::: "memory")
#define BAR  __builtin_amdgcn_s_barrier()

template <int EPI>
__global__ __launch_bounds__(512, 2) void gemm256(const u16* __restrict__ A,
                                                  const u16* __restrict__ W,
                                                  int M, int N, int K,
                                                  u16* outb, float* outf,
                                                  float* outf2, const float* res,
                                                  u16* vtw, int ksplit) {
    __shared__ u16 lds_[32768];
    char* ldsb = (char*)lds_;
    const int tid = threadIdx.x;
    const int w = tid >> 6, l = tid & 63;
    const int wr8 = (w >> 2) * 8;
    const int wc4 = (w & 3) * 4;
    const int rin64 = (l & 15) * 64;
    const int cst2 = ((((l >> 4) * 8) ^ (((l >> 3) & 1) << 4)) << 1);

    const int nbn = N >> 8;
    const int nbm = M >> 8;
    const int nwg = gridDim.x;
    const int cpx = nwg >> 3;
    const int bid = blockIdx.x;
    int wg = (bid & 7) * cpx + (bid >> 3);
    int kseg = 0;
    int Keff = K;
    if (ksplit == 2) {
        kseg = wg & 1;
        wg >>= 1;
        Keff = K >> 1;
    }
    const int grp = 8 * nbn;
    const int g8 = wg / grp;
    const int rem = wg - g8 * grp;
    const int bm0 = g8 * 8;
    const int gmh = (nbm - bm0 < 8) ? (nbm - bm0) : 8;
    const int bn = rem / gmh;
    const int bm = bm0 + rem % gmh;
    const u16* Ab = A + (long)kseg * Keff;
    const u16* Wb = W + (long)kseg * Keff;

    const int r4 = l >> 2;
    const int clog = ((l & 3) * 8) ^ (((r4 >> 3) & 1) << 4);
    const u16* sA0 = Ab + ((long)bm * 256 + (w * 2 + 0) * 16 + r4) * K + clog;
    const u16* sA1 = Ab + ((long)bm * 256 + (w * 2 + 1) * 16 + r4) * K + clog;
    const u16* sB0 = Wb + ((long)bn * 256 + (w * 2 + 0) * 16 + r4) * K + clog;
    const u16* sB1 = Wb + ((long)bn * 256 + (w * 2 + 1) * 16 + r4) * K + clog;

    f32x4 acc[8][4];
    #pragma unroll
    for (int m = 0; m < 8; ++m)
        #pragma unroll
        for (int n = 0; n < 4; ++n) acc[m][n] = (f32x4){0.f, 0.f, 0.f, 0.f};
    bf16x8 afc[4], afn[4], bfc[4], bfn[4];

    const int nkt = Keff >> 5;          // K-tiles of 32
    const int niter = nkt >> 1;

    // prologue
    STAGE_A(0, 0); STAGE_B(0, 0); STAGE_A(1, 1); STAGE_B(1, 1);
    asm volatile("s_waitcnt vmcnt(4)" ::: "memory");
    BAR;
    PREF_A(afc, 0, 0); PREF_B(bfc, 0);
    BAR;

    for (int it = 0; it < niter; ++it) {
        const int t = it * 2;
        const int t2 = (t + 2 < nkt) ? t + 2 : nkt - 1;
        const int t3 = (t + 3 < nkt) ? t + 3 : nkt - 1;
        // P1
        PREF_A(afn, 0, 1);
        STAGE_B(0, t2);
        MFMA_Q(0, afc, bfc);
        VMC2;
        BAR;
        // P2
        PREF_A(afc, 1, 0); PREF_B(bfn, 1);
        STAGE_A(0, t2);
        MFMA_Q(1, afn, bfc);
        BAR;
        // P3
        PREF_A(afn, 1, 1);
        STAGE_B(1, t3);
        MFMA_Q(0, afc, bfn);
        VMC2;
        BAR;
        // P4
        PREF_A(afc, 0, 0); PREF_B(bfc, 0);
        STAGE_A(1, t3);
        MFMA_Q(1, afn, bfn);
        BAR;
    }
    asm volatile("s_waitcnt vmcnt(0)" ::: "memory");

    // epilogue
    const int rb = bm * 256 + (wr8 >> 3) * 128 + ((l >> 4) << 2);
    const int cb = bn * 256 + (w & 3) * 64 + (l & 15);
    if (EPI == 4) {
        const bool vreg = (cb >= 4096);
        #pragma unroll
        for (int m = 0; m < 8; ++m) {
            long row0 = rb + m * 16;
            #pragma unroll
            for (int n = 0; n < 4; ++n) {
                long col = cb + n * 16;
                if (vreg) {
                    int d = (int)col & 127;
                    int hh = ((int)col >> 7) - 32;
                    long bh = (row0 >> 11) * 16 + hh;
                    int s = (int)(row0 & 2047);
                    u16x4 o4;
                    #pragma unroll
                    for (int r = 0; r < 4; ++r) o4[r] = f2b(acc[m][n][r]);
                    *(u16x4*)(vtw + (bh * 128 + d) * 2048 + s) = o4;
                } else {
                    #pragma unroll
                    for (int r = 0; r < 4; ++r)
                        outb[(row0 + r) * N + col] = f2b(acc[m][n][r]);
                }
            }
        }
        return;
    }
    float* pf = (EPI == 3) ? (kseg ? outf2 : outf) : outf;
    #pragma unroll
    for (int m = 0; m < 8; ++m) {
        #pragma unroll
        for (int r = 0; r < 4; ++r) {
            long row = rb + m * 16 + r;
            #pragma unroll
            for (int n = 0; n < 4; ++n) {
                long col = cb + n * 16;
                float v = acc[m][n][r];
                if (EPI == 1) {
                    pf[row * N + col] = res[row * N + col] + v;
                } else if (EPI == 2) {
                    float u = 0.7978845608028654f * v * (1.0f + 0.044715f * v * v);
                    float e = __expf(2.0f * u);
                    float tgl = 1.0f - 2.0f / (e + 1.0f);
                    outb[row * N + col] = f2b(0.5f * v * (1.0f + tgl));
                } else if (EPI == 3) {
                    pf[row * N + col] = v;
                } else {
                    outb[row * N + col] = f2b(v);
                }
            }
        }
    }
}

// ---------------- causal flash attention v4: balanced q-tile pairing ---------
struct AttnState {
    f32x16 acc[4];
    float m_i, l_i;
};

template <bool DIAG>
static __device__ __forceinline__ void attn_tile(
    int kv0, int qg, bool do_g1, int l31, int hi,
    const u16* __restrict__ Ks, const u16* __restrict__ Vt,
    const bf16x8 (&qf)[8], AttnState& st)
{
    f32x16 sacc0, sacc1;
    #pragma unroll
    for (int r = 0; r < 16; ++r) { sacc0[r] = 0.f; sacc1[r] = 0.f; }

    __builtin_amdgcn_s_setprio(1);
    #pragma unroll
    for (int dsl = 0; dsl < 8; ++dsl) {
        int slot = dsl * 2 + hi;
        int kv = l31;
        int sw = (slot & 8) | ((slot & 7) ^ (kv & 7));
        bf16x8 kf = *(const bf16x8*)(Ks + kv * 128 + sw * 8);
        sacc0 = MFMA32(kf, qf[dsl], sacc0, 0, 0, 0);
    }
    if (do_g1) {
        #pragma unroll
        for (int dsl = 0; dsl < 8; ++dsl) {
            int slot = dsl * 2 + hi;
            int kv = 32 + l31;
            int sw = (slot & 8) | ((slot & 7) ^ (kv & 7));
            bf16x8 kf = *(const bf16x8*)(Ks + kv * 128 + sw * 8);
            sacc1 = MFMA32(kf, qf[dsl], sacc1, 0, 0, 0);
        }
    }
    __builtin_amdgcn_s_setprio(0);

    float sv[2][16];
    #pragma unroll
    for (int r = 0; r < 16; ++r) {
        sv[0][r] = sacc0[r];
        sv[1][r] = do_g1 ? sacc1[r] : -INFINITY;
    }
    if (DIAG) {
        #pragma unroll
        for (int g = 0; g < 2; ++g)
            #pragma unroll
            for (int r = 0; r < 16; ++r) {
                int kvg = kv0 + g * 32 + ((r & 3) + 8 * (r >> 2) + 4 * hi);
                if (kvg > qg) sv[g][r] = -INFINITY;
            }
    }

    float mx = sv[0][0];
    #pragma unroll
    for (int r = 1; r < 16; ++r) mx = fmaxf(mx, sv[0][r]);
    #pragma unroll
    for (int r = 0; r < 16; ++r) mx = fmaxf(mx, sv[1][r]);
    mx = fmaxf(mx, __shfl_xor(mx, 32));

    bool defer = __all(mx <= st.m_i + 8.0f);
    if (!defer) {
        float mnew = fmaxf(st.m_i, mx);
        float f = __expf(st.m_i - mnew);
        st.l_i *= f;
        #pragma unroll
        for (int dblk = 0; dblk < 4; ++dblk)
            #pragma unroll
            for (int r = 0; r < 16; ++r) st.acc[dblk][r] *= f;
        st.m_i = mnew;
    }

    float ssum = 0.f;
    #pragma unroll
    for (int g = 0; g < 2; ++g)
        #pragma unroll
        for (int r = 0; r < 16; ++r) {
            float e = __expf(sv[g][r] - st.m_i);
            sv[g][r] = e;
            ssum += e;
        }
    ssum += __shfl_xor(ssum, 32);
    st.l_i += ssum;

    unsigned w[2][4][2];
    #pragma unroll
    for (int g = 0; g < 2; ++g)
        #pragma unroll
        for (int q4 = 0; q4 < 4; ++q4) {
            w[g][q4][0] = pk2(sv[g][4 * q4 + 0], sv[g][4 * q4 + 1]);
            w[g][q4][1] = pk2(sv[g][4 * q4 + 2], sv[g][4 * q4 + 3]);
        }
    bf16x8 pfrag[4];
    #pragma unroll
    for (int ks = 0; ks < 4; ++ks) {
        int g = ks >> 1, h2 = ks & 1;
        unsigned o0 = hi ? w[g][2 * h2 + 1][0] : w[g][2 * h2][0];
        unsigned o1 = hi ? w[g][2 * h2 + 1][1] : w[g][2 * h2][1];
        unsigned t0 = hi ? w[g][2 * h2][0] : w[g][2 * h2 + 1][0];
        unsigned t1 = hi ? w[g][2 * h2][1] : w[g][2 * h2 + 1][1];
        unsigned s0v = __shfl_xor(t0, 32);
        unsigned s1v = __shfl_xor(t1, 32);
        union { unsigned u[4]; bf16x8 v; } cv;
        cv.u[0] = hi ? s0v : o0;
        cv.u[1] = hi ? s1v : o1;
        cv.u[2] = hi ? o0 : s0v;
        cv.u[3] = hi ? o1 : s1v;
        pfrag[ks] = cv.v;
    }

    __builtin_amdgcn_s_setprio(1);
    #pragma unroll
    for (int dblk = 0; dblk < 4; ++dblk) {
        int d = dblk * 32 + l31;
        #pragma unroll
        for (int ks = 0; ks < 4; ++ks) {
            if (ks >= 2 && !do_g1) continue;
            int slot = ks * 2 + hi;
            bf16x8 vf = *(const bf16x8*)(Vt + d * 64 + (slot ^ (d & 7)) * 8);
            st.acc[dblk] = MFMA32(vf, pfrag[ks], st.acc[dblk], 0, 0, 0);
        }
    }
    __builtin_amdgcn_s_setprio(0);
}

__global__ __launch_bounds__(256) void attn4_k(const u16* __restrict__ qkv,
                                               const u16* __restrict__ vt,
                                               u16* __restrict__ out) {
    const int bh = blockIdx.y;            // 0..31
    const int b = bh >> 4, h = bh & 15;
    const int j = (blockIdx.y & 16) ? (15 - blockIdx.x) : blockIdx.x;
    const int jA = j, jB = 31 - j;        // 64-row q-tile indices
    const int tid = threadIdx.x, wave = tid >> 6, lane = tid & 63;
    const int l31 = lane & 31, hi = lane >> 5;
    const int brow = b * 2048;
    __shared__ u16 Ks_lds[2][64 * 128];
    __shared__ u16 Vt_lds[2][128 * 64];

    const int krow = tid >> 4;
    const int kslot = tid & 15;
    const int vrow = tid >> 3;
    const int vslot = tid & 7;

    const int r0 = (wave < 2) ? (jA * 64 + wave * 32)
                              : (jB * 64 + (wave - 2) * 32);
    const int qg = r0 + l31;

    bf16x8 qf[8];
    {
        const u16* qp = qkv + (long)(brow + r0 + l31) * 6144 + h * 128 + hi * 8;
        #pragma unroll
        for (int dsl = 0; dsl < 8; ++dsl) qf[dsl] = *(const bf16x8*)(qp + dsl * 16);
    }

    AttnState st;
    st.m_i = -INFINITY; st.l_i = 0.f;
    #pragma unroll
    for (int dblk = 0; dblk < 4; ++dblk)
        #pragma unroll
        for (int r = 0; r < 16; ++r) st.acc[dblk][r] = 0.f;

    const int nt = jB + 1;                // kv tiles 0..jB
    int cur = 0;

#define STAGE_KV(BUF, KV0) do { \
    _Pragma("unroll") \
    for (int i = 0; i < 4; ++i) { \
        int kv = i * 16 + krow; \
        int sw = (kslot & 8) | ((kslot & 7) ^ (kv & 7)); \
        const u16* src = qkv + (long)(brow + (KV0) + kv) * 6144 + 2048 + \
                         h * 128 + sw * 8; \
        gload_lds16(src, (char*)Ks_lds[BUF] + (i * 16 + wave * 4) * 256); \
    } \
    _Pragma("unroll") \
    for (int i = 0; i < 4; ++i) { \
        int d = i * 32 + vrow; \
        int sw = vslot ^ (d & 7); \
        const u16* src = vt + ((long)bh * 128 + d) * 2048 + (KV0) + sw * 8; \
        gload_lds16(src, (char*)Vt_lds[BUF] + (i * 32 + wave * 8) * 128); \
    } \
} while (0)

    STAGE_KV(0, 0);
    for (int t = 0; t < nt; ++t) {
        const int kv0 = t * 64;
        const bool more = (t + 1 < nt);
        if (more) {
            if (cur) STAGE_KV(0, kv0 + 64); else STAGE_KV(1, kv0 + 64);
        }
        if (more) { asm volatile("s_waitcnt vmcnt(8)" ::: "memory"); }
        else      { asm volatile("s_waitcnt vmcnt(0)" ::: "memory"); }
        __builtin_amdgcn_sched_barrier(0);
        __builtin_amdgcn_s_barrier();
        __builtin_amdgcn_sched_barrier(0);
        {
            const u16* Ks = Ks_lds[cur];
            const u16* Vt_ = Vt_lds[cur];
            const int delta = r0 - kv0;
            if (delta >= 64)
                attn_tile<false>(kv0, qg, true, l31, hi, Ks, Vt_, qf, st);
            else if (delta >= 0)
                attn_tile<true>(kv0, qg, delta >= 32, l31, hi, Ks, Vt_, qf, st);
        }
        __builtin_amdgcn_sched_barrier(0);
        __builtin_amdgcn_s_barrier();
        __builtin_amdgcn_sched_barrier(0);
        cur ^= 1;
    }
#undef STAGE_KV

    float inv = 1.0f / st.l_i;
    long orow = (long)(brow + r0 + l31);
    #pragma unroll
    for (int dblk = 0; dblk < 4; ++dblk)
        #pragma unroll
        for (int rq = 0; rq < 4; ++rq) {
            u16x4 o4;
            #pragma unroll
            for (int m = 0; m < 4; ++m) o4[m] = f2b(st.acc[dblk][rq * 4 + m] * inv);
            int d = dblk * 32 + 8 * rq + 4 * hi;
            *(u16x4*)(out + orow * 2048 + h * 128 + d) = o4;
        }
}

// ---------------- launch --------------------------------------------------
extern "C" void kernel_launch(void* const* d_in, const int* in_sizes, int n_in,
                              void* d_out, int out_size, void* d_ws, size_t ws_size,
                              hipStream_t stream) {
    const float* x     = (const float*)d_in[0];
    const float* cosb  = (const float*)d_in[1];
    const float* sinb  = (const float*)d_in[2];
    const float* g1    = (const float*)d_in[3];
    const float* g2    = (const float*)d_in[4];
    const float* w_qkv = (const float*)d_in[5];
    const float* w_out = (const float*)d_in[6];
    const float* w_fc1 = (const float*)d_in[7];
    const float* w_fc2 = (const float*)d_in[8];

    char* ws = (char*)d_ws;
    u16* wqkv_b = (u16*)(ws);                    // 6144x2048 bf16
    u16* wout_b = (u16*)(ws + 25165824);         // 2048x2048
    u16* wfc1_b = (u16*)(ws + 33554432);         // 8192x2048
    u16* wfc2_b = (u16*)(ws + 67108864);         // 2048x8192
    u16* h_b    = (u16*)(ws + 100663296);        // 4096x2048 (h1 / h2)
    u16* qkv_b  = (u16*)(ws + 117440512);        // 4096x6144 (q,k; v -> vt)
    u16* attn_b = (u16*)(ws + 167772160);        // 4096x2048
    u16* hg_b   = qkv_b;                         // 4096x8192 (fc1 out)
    u16* vt_b   = (u16*)d_out;                   // 32x128x2048 bf16 (16.7MB),
                                                 // d_out dead until addrednorm
    float* p0op = (float*)d_out;                 // out-proj partial 0 (33.5MB,
                                                 // overwrites dead vt; addrednorm
                                                 // self-aliases xout==p0 per-thread)
    float* p1op = (float*)(ws + 117440512);      // out-proj partial 1 (dead qkv)
    float* part = (float*)ws;                    // fc2 partials over dead weights
    float* xout = (float*)d_out;

    cvt4_k<<<49152, 256, 0, stream>>>(w_qkv, w_out, w_fc1, w_fc2, (u16*)ws);

    rmsnorm_k<<<4096, 256, 0, stream>>>(x, g1, h_b);
    gemm256<4><<<384, 512, 0, stream>>>(h_b, wqkv_b, 4096, 6144, 2048,
                                        qkv_b, nullptr, nullptr, nullptr,
                                        vt_b, 1);
    rope_k<<<8192, 256, 0, stream>>>(qkv_b, cosb, sinb);
    attn4_k<<<dim3(16, 32), 256, 0, stream>>>(qkv_b, vt_b, attn_b);
    gemm256<3><<<256, 512, 0, stream>>>(attn_b, wout_b, 4096, 2048, 2048,
                                        nullptr, p0op, p1op, nullptr,
                                        nullptr, 2);
    addrednorm_k<<<4096, 256, 0, stream>>>(xout, x, p0op, p1op, g2, h_b);
    gemm256<2><<<512, 512, 0, stream>>>(h_b, wfc1_b, 4096, 8192, 2048,
                                        hg_b, nullptr, nullptr, nullptr,
                                        nullptr, 1);
    gemm256<3><<<256, 512, 0, stream>>>(hg_b, wfc2_b, 4096, 2048, 8192,
                                        nullptr, part, part + 8388608, nullptr,
                                        nullptr, 2);
    addred_k<<<8192, 256, 0, stream>>>(xout, part, part + 8388608);
}

// Round 19
// 568.210 us; speedup vs baseline: 1.0347x; 1.0071x over previous
//
#include <hip/hip_runtime.h>
#include <stdint.h>

typedef unsigned short u16;
typedef u16 u16x4 __attribute__((ext_vector_type(4)));
typedef u16 u16x8 __attribute__((ext_vector_type(8)));
typedef __bf16 bf16x8 __attribute__((ext_vector_type(8)));
typedef float f32x4 __attribute__((ext_vector_type(4)));
typedef float f32x16 __attribute__((ext_vector_type(16)));

#define MFMA16 __builtin_amdgcn_mfma_f32_16x16x32_bf16
#define MFMA32 __builtin_amdgcn_mfma_f32_32x32x16_bf16

static __device__ __forceinline__ float b2f(u16 u) {
    union { unsigned int i; float f; } v; v.i = ((unsigned int)u) << 16; return v.f;
}
static __device__ __forceinline__ u16 f2b(float f) {
    union { float f; unsigned int i; } v; v.f = f;
    unsigned int r = (v.i + 0x7fffu + ((v.i >> 16) & 1u)) >> 16;
    return (u16)r;
}
static __device__ __forceinline__ unsigned pk2(float lo, float hi) {
    union { __bf16 b[2]; unsigned u; } t;
    t.b[0] = (__bf16)lo; t.b[1] = (__bf16)hi; return t.u;
}
static __device__ __forceinline__ void gload_lds16(const void* g, void* l) {
    __builtin_amdgcn_global_load_lds((__attribute__((address_space(1))) void*)g,
                                     (__attribute__((address_space(3))) void*)l,
                                     16, 0, 0);
}

// ---- fused: weights fp32->bf16 (blocks 0..49151) + rmsnorm1 (blocks 49152+) -
// cvt writes ws[0..100.7MB); rmsnorm reads x, writes h_b at ws+100.7MB:
// fully disjoint, so the two phases can share one dispatch.
__global__ __launch_bounds__(256) void cvtnorm_k(const float* __restrict__ s0,
                                                 const float* __restrict__ s1,
                                                 const float* __restrict__ s2,
                                                 const float* __restrict__ s3,
                                                 u16* __restrict__ out,
                                                 const float* __restrict__ x,
                                                 const float* __restrict__ g,
                                                 u16* __restrict__ outh) {
    if (blockIdx.x < 49152) {
        long i = ((long)blockIdx.x * 256 + threadIdx.x) * 4;  // < 50331648
        const float* src; long off;
        if (i < 12582912)      { src = s0; off = i; }
        else if (i < 16777216) { src = s1; off = i - 12582912; }
        else if (i < 33554432) { src = s2; off = i - 16777216; }
        else                   { src = s3; off = i - 33554432; }
        float4 v = *(const float4*)(src + off);
        u16x4 o; o[0] = f2b(v.x); o[1] = f2b(v.y);
        o[2] = f2b(v.z); o[3] = f2b(v.w);
        *(u16x4*)(out + i) = o;
        return;
    }
    const long row = blockIdx.x - 49152;
    const int tid = threadIdx.x;
    const float* xr = x + row * 2048;
    float4 a = *(const float4*)(xr + tid * 4);
    float4 b = *(const float4*)(xr + 1024 + tid * 4);
    float ss = a.x*a.x + a.y*a.y + a.z*a.z + a.w*a.w
             + b.x*b.x + b.y*b.y + b.z*b.z + b.w*b.w;
    #pragma unroll
    for (int d = 1; d < 64; d <<= 1) ss += __shfl_xor(ss, d);
    __shared__ float red[4];
    if ((tid & 63) == 0) red[tid >> 6] = ss;
    __syncthreads();
    float tot = red[0] + red[1] + red[2] + red[3];
    float rinv = rsqrtf(tot * (1.0f / 2048.0f) + 1e-6f);
    float4 g0 = *(const float4*)(g + tid * 4);
    float4 g1 = *(const float4*)(g + 1024 + tid * 4);
    u16x4 o0, o1;
    o0[0] = f2b(a.x * g0.x * rinv); o0[1] = f2b(a.y * g0.y * rinv);
    o0[2] = f2b(a.z * g0.z * rinv); o0[3] = f2b(a.w * g0.w * rinv);
    o1[0] = f2b(b.x * g1.x * rinv); o1[1] = f2b(b.y * g1.y * rinv);
    o1[2] = f2b(b.z * g1.z * rinv); o1[3] = f2b(b.w * g1.w * rinv);
    *(u16x4*)(outh + row * 2048 + tid * 4) = o0;
    *(u16x4*)(outh + row * 2048 + 1024 + tid * 4) = o1;
}

// ---------------- split-K reduce: xout += p0 + p1 ----------------------------
__global__ __launch_bounds__(256) void addred_k(float* __restrict__ xout,
                                                const float* __restrict__ p0,
                                                const float* __restrict__ p1) {
    long i = ((long)blockIdx.x * 256 + threadIdx.x) * 4;
    float4 a = *(const float4*)(xout + i);
    float4 b = *(const float4*)(p0 + i);
    float4 c = *(const float4*)(p1 + i);
    a.x += b.x + c.x; a.y += b.y + c.y; a.z += b.z + c.z; a.w += b.w + c.w;
    *(float4*)(xout + i) = a;
}

// ---- fused: xout = x + p0 + p1; h = rmsnorm(xout)*g  (xout MAY alias p0) ----
__global__ __launch_bounds__(256) void addrednorm_k(float* xout,
                                                    const float* __restrict__ x,
                                                    const float* p0,
                                                    const float* __restrict__ p1,
                                                    const float* __restrict__ g,
                                                    u16* __restrict__ out) {
    const long row = blockIdx.x;
    const int tid = threadIdx.x;
    const long base = row * 2048;
    float4 a = *(const float4*)(x + base + tid * 4);
    float4 b = *(const float4*)(p0 + base + tid * 4);
    float4 c = *(const float4*)(p1 + base + tid * 4);
    a.x += b.x + c.x; a.y += b.y + c.y; a.z += b.z + c.z; a.w += b.w + c.w;
    float4 a2 = *(const float4*)(x + base + 1024 + tid * 4);
    float4 b2 = *(const float4*)(p0 + base + 1024 + tid * 4);
    float4 c2 = *(const float4*)(p1 + base + 1024 + tid * 4);
    a2.x += b2.x + c2.x; a2.y += b2.y + c2.y;
    a2.z += b2.z + c2.z; a2.w += b2.w + c2.w;
    *(float4*)(xout + base + tid * 4) = a;
    *(float4*)(xout + base + 1024 + tid * 4) = a2;
    float ss = a.x*a.x + a.y*a.y + a.z*a.z + a.w*a.w
             + a2.x*a2.x + a2.y*a2.y + a2.z*a2.z + a2.w*a2.w;
    #pragma unroll
    for (int d = 1; d < 64; d <<= 1) ss += __shfl_xor(ss, d);
    __shared__ float red[4];
    if ((tid & 63) == 0) red[tid >> 6] = ss;
    __syncthreads();
    float tot = red[0] + red[1] + red[2] + red[3];
    float rinv = rsqrtf(tot * (1.0f / 2048.0f) + 1e-6f);
    float4 g0 = *(const float4*)(g + tid * 4);
    float4 g1 = *(const float4*)(g + 1024 + tid * 4);
    u16x4 o0, o1;
    o0[0] = f2b(a.x * g0.x * rinv); o0[1] = f2b(a.y * g0.y * rinv);
    o0[2] = f2b(a.z * g0.z * rinv); o0[3] = f2b(a.w * g0.w * rinv);
    o1[0] = f2b(a2.x * g1.x * rinv); o1[1] = f2b(a2.y * g1.y * rinv);
    o1[2] = f2b(a2.z * g1.z * rinv); o1[3] = f2b(a2.w * g1.w * rinv);
    *(u16x4*)(out + base + tid * 4) = o0;
    *(u16x4*)(out + base + 1024 + tid * 4) = o1;
}

// ---------------- RoPE in-place on bf16 qkv (q,k only); q pre-scaled ---------
__global__ __launch_bounds__(256) void rope_k(u16* __restrict__ qkv,
                                              const float* __restrict__ cosb,
                                              const float* __restrict__ sinb) {
    long idx = (long)blockIdx.x * 256 + threadIdx.x;
    int d = (int)(idx & 15) * 4;
    int h = (int)((idx >> 4) & 15);
    int which = (int)((idx >> 8) & 1);
    long row = idx >> 9;
    int s = (int)(row & 2047);
    u16* base = qkv + row * 6144 + which * 2048 + h * 128;
    u16x4 ua = *(u16x4*)(base + d);
    u16x4 ub = *(u16x4*)(base + d + 64);
    float4 c4 = *(const float4*)(cosb + (long)s * 128 + d);
    float4 s4 = *(const float4*)(sinb + (long)s * 128 + d);
    float cc[4] = {c4.x, c4.y, c4.z, c4.w};
    float sn[4] = {s4.x, s4.y, s4.z, s4.w};
    float scale = (which == 0) ? 0.08838834764831845f : 1.0f;
    u16x4 oa, ob;
    #pragma unroll
    for (int j = 0; j < 4; ++j) {
        float a = b2f(ua[j]), b = b2f(ub[j]);
        oa[j] = f2b((a * cc[j] - b * sn[j]) * scale);
        ob[j] = f2b((b * cc[j] + a * sn[j]) * scale);
    }
    *(u16x4*)(base + d) = oa;
    *(u16x4*)(base + d + 64) = ob;
}

// ---------------- GEMM 256x256, BK=32 / 4-phase / 64KB LDS -------------------
// 512 thr = 8 waves (2M x 4N). Register fragment double-buffer (counted lgkm);
// vmcnt(2) at P1/P3 ends; one barrier per phase. Best measured config (r14).
#define DS_A(BUF, SM) (*(const bf16x8*)(ldsb + (BUF)*16384 + ((SM) << 10) + rin64 + cst2))
#define DS_B(BUF, SN) (*(const bf16x8*)(ldsb + 32768 + (BUF)*16384 + ((SN) << 10) + rin64 + cst2))
#define STAGE_A(BUF, KT) do { \
    gload_lds16(sA0 + ((long)(KT)*32), ldsb + (BUF)*16384 + (w*2)*1024); \
    gload_lds16(sA1 + ((long)(KT)*32), ldsb + (BUF)*16384 + (w*2+1)*1024); \
} while (0)
#define STAGE_B(BUF, KT) do { \
    gload_lds16(sB0 + ((long)(KT)*32), ldsb + 32768 + (BUF)*16384 + (w*2)*1024); \
    gload_lds16(sB1 + ((long)(KT)*32), ldsb + 32768 + (BUF)*16384 + (w*2+1)*1024); \
} while (0)
#define PREF_A(DST, BUF, MH) do { \
    _Pragma("unroll") \
    for (int m = 0; m < 4; ++m) DST[m] = DS_A(BUF, wr8 + (MH)*4 + m); \
} while (0)
#define PREF_B(DST, BUF) do { \
    _Pragma("unroll") \
    for (int n = 0; n < 4; ++n) DST[n] = DS_B(BUF, wc4 + n); \
} while (0)
#define MFMA_Q(MH, AF, BF) do { \
    __builtin_amdgcn_s_setprio(1); \
    _Pragma("unroll") \
    for (int m = 0; m < 4; ++m) \
        _Pragma("unroll") \
        for (int n = 0; n < 4; ++n) \
            acc[(MH)*4 + m][n] = MFMA16(AF[m], BF[n], acc[(MH)*4 + m][n], 0, 0, 0); \
    __builtin_amdgcn_s_setprio(0); \
} while (0)
#define VMC2 asm volatile("s_waitcnt vmcnt(2)" ::: "memory")
#define BAR  __builtin_amdgcn_s_barrier()

template <int EPI>
__global__ __launch_bounds__(512, 2) void gemm256(const u16* __restrict__ A,
                                                  const u16* __restrict__ W,
                                                  int M, int N, int K,
                                                  u16* outb, float* outf,
                                                  float* outf2, const float* res,
                                                  u16* vtw, int ksplit) {
    __shared__ u16 lds_[32768];
    char* ldsb = (char*)lds_;
    const int tid = threadIdx.x;
    const int w = tid >> 6, l = tid & 63;
    const int wr8 = (w >> 2) * 8;
    const int wc4 = (w & 3) * 4;
    const int rin64 = (l & 15) * 64;
    const int cst2 = ((((l >> 4) * 8) ^ (((l >> 3) & 1) << 4)) << 1);

    const int nbn = N >> 8;
    const int nbm = M >> 8;
    const int nwg = gridDim.x;
    const int cpx = nwg >> 3;
    const int bid = blockIdx.x;
    int wg = (bid & 7) * cpx + (bid >> 3);
    int kseg = 0;
    int Keff = K;
    if (ksplit == 2) {
        kseg = wg & 1;
        wg >>= 1;
        Keff = K >> 1;
    }
    const int grp = 8 * nbn;
    const int g8 = wg / grp;
    const int rem = wg - g8 * grp;
    const int bm0 = g8 * 8;
    const int gmh = (nbm - bm0 < 8) ? (nbm - bm0) : 8;
    const int bn = rem / gmh;
    const int bm = bm0 + rem % gmh;
    const u16* Ab = A + (long)kseg * Keff;
    const u16* Wb = W + (long)kseg * Keff;

    const int r4 = l >> 2;
    const int clog = ((l & 3) * 8) ^ (((r4 >> 3) & 1) << 4);
    const u16* sA0 = Ab + ((long)bm * 256 + (w * 2 + 0) * 16 + r4) * K + clog;
    const u16* sA1 = Ab + ((long)bm * 256 + (w * 2 + 1) * 16 + r4) * K + clog;
    const u16* sB0 = Wb + ((long)bn * 256 + (w * 2 + 0) * 16 + r4) * K + clog;
    const u16* sB1 = Wb + ((long)bn * 256 + (w * 2 + 1) * 16 + r4) * K + clog;

    f32x4 acc[8][4];
    #pragma unroll
    for (int m = 0; m < 8; ++m)
        #pragma unroll
        for (int n = 0; n < 4; ++n) acc[m][n] = (f32x4){0.f, 0.f, 0.f, 0.f};
    bf16x8 afc[4], afn[4], bfc[4], bfn[4];

    const int nkt = Keff >> 5;          // K-tiles of 32
    const int niter = nkt >> 1;

    // prologue
    STAGE_A(0, 0); STAGE_B(0, 0); STAGE_A(1, 1); STAGE_B(1, 1);
    asm volatile("s_waitcnt vmcnt(4)" ::: "memory");
    BAR;
    PREF_A(afc, 0, 0); PREF_B(bfc, 0);
    BAR;

    for (int it = 0; it < niter; ++it) {
        const int t = it * 2;
        const int t2 = (t + 2 < nkt) ? t + 2 : nkt - 1;
        const int t3 = (t + 3 < nkt) ? t + 3 : nkt - 1;
        // P1
        PREF_A(afn, 0, 1);
        STAGE_B(0, t2);
        MFMA_Q(0, afc, bfc);
        VMC2;
        BAR;
        // P2
        PREF_A(afc, 1, 0); PREF_B(bfn, 1);
        STAGE_A(0, t2);
        MFMA_Q(1, afn, bfc);
        BAR;
        // P3
        PREF_A(afn, 1, 1);
        STAGE_B(1, t3);
        MFMA_Q(0, afc, bfn);
        VMC2;
        BAR;
        // P4
        PREF_A(afc, 0, 0); PREF_B(bfc, 0);
        STAGE_A(1, t3);
        MFMA_Q(1, afn, bfn);
        BAR;
    }
    asm volatile("s_waitcnt vmcnt(0)" ::: "memory");

    // epilogue
    const int rb = bm * 256 + (wr8 >> 3) * 128 + ((l >> 4) << 2);
    const int cb = bn * 256 + (w & 3) * 64 + (l & 15);
    if (EPI == 4) {
        const bool vreg = (cb >= 4096);
        #pragma unroll
        for (int m = 0; m < 8; ++m) {
            long row0 = rb + m * 16;
            #pragma unroll
            for (int n = 0; n < 4; ++n) {
                long col = cb + n * 16;
                if (vreg) {
                    int d = (int)col & 127;
                    int hh = ((int)col >> 7) - 32;
                    long bh = (row0 >> 11) * 16 + hh;
                    int s = (int)(row0 & 2047);
                    u16x4 o4;
                    #pragma unroll
                    for (int r = 0; r < 4; ++r) o4[r] = f2b(acc[m][n][r]);
                    *(u16x4*)(vtw + (bh * 128 + d) * 2048 + s) = o4;
                } else {
                    #pragma unroll
                    for (int r = 0; r < 4; ++r)
                        outb[(row0 + r) * N + col] = f2b(acc[m][n][r]);
                }
            }
        }
        return;
    }
    float* pf = (EPI == 3) ? (kseg ? outf2 : outf) : outf;
    #pragma unroll
    for (int m = 0; m < 8; ++m) {
        #pragma unroll
        for (int r = 0; r < 4; ++r) {
            long row = rb + m * 16 + r;
            #pragma unroll
            for (int n = 0; n < 4; ++n) {
                long col = cb + n * 16;
                float v = acc[m][n][r];
                if (EPI == 1) {
                    pf[row * N + col] = res[row * N + col] + v;
                } else if (EPI == 2) {
                    float u = 0.7978845608028654f * v * (1.0f + 0.044715f * v * v);
                    float e = __expf(2.0f * u);
                    float tgl = 1.0f - 2.0f / (e + 1.0f);
                    outb[row * N + col] = f2b(0.5f * v * (1.0f + tgl));
                } else if (EPI == 3) {
                    pf[row * N + col] = v;
                } else {
                    outb[row * N + col] = f2b(v);
                }
            }
        }
    }
}

// ---------------- causal flash attention v4: balanced q-tile pairing ---------
struct AttnState {
    f32x16 acc[4];
    float m_i, l_i;
};

template <bool DIAG>
static __device__ __forceinline__ void attn_tile(
    int kv0, int qg, bool do_g1, int l31, int hi,
    const u16* __restrict__ Ks, const u16* __restrict__ Vt,
    const bf16x8 (&qf)[8], AttnState& st)
{
    f32x16 sacc0, sacc1;
    #pragma unroll
    for (int r = 0; r < 16; ++r) { sacc0[r] = 0.f; sacc1[r] = 0.f; }

    __builtin_amdgcn_s_setprio(1);
    #pragma unroll
    for (int dsl = 0; dsl < 8; ++dsl) {
        int slot = dsl * 2 + hi;
        int kv = l31;
        int sw = (slot & 8) | ((slot & 7) ^ (kv & 7));
        bf16x8 kf = *(const bf16x8*)(Ks + kv * 128 + sw * 8);
        sacc0 = MFMA32(kf, qf[dsl], sacc0, 0, 0, 0);
    }
    if (do_g1) {
        #pragma unroll
        for (int dsl = 0; dsl < 8; ++dsl) {
            int slot = dsl * 2 + hi;
            int kv = 32 + l31;
            int sw = (slot & 8) | ((slot & 7) ^ (kv & 7));
            bf16x8 kf = *(const bf16x8*)(Ks + kv * 128 + sw * 8);
            sacc1 = MFMA32(kf, qf[dsl], sacc1, 0, 0, 0);
        }
    }
    __builtin_amdgcn_s_setprio(0);

    float sv[2][16];
    #pragma unroll
    for (int r = 0; r < 16; ++r) {
        sv[0][r] = sacc0[r];
        sv[1][r] = do_g1 ? sacc1[r] : -INFINITY;
    }
    if (DIAG) {
        #pragma unroll
        for (int g = 0; g < 2; ++g)
            #pragma unroll
            for (int r = 0; r < 16; ++r) {
                int kvg = kv0 + g * 32 + ((r & 3) + 8 * (r >> 2) + 4 * hi);
                if (kvg > qg) sv[g][r] = -INFINITY;
            }
    }

    float mx = sv[0][0];
    #pragma unroll
    for (int r = 1; r < 16; ++r) mx = fmaxf(mx, sv[0][r]);
    #pragma unroll
    for (int r = 0; r < 16; ++r) mx = fmaxf(mx, sv[1][r]);
    mx = fmaxf(mx, __shfl_xor(mx, 32));

    bool defer = __all(mx <= st.m_i + 8.0f);
    if (!defer) {
        float mnew = fmaxf(st.m_i, mx);
        float f = __expf(st.m_i - mnew);
        st.l_i *= f;
        #pragma unroll
        for (int dblk = 0; dblk < 4; ++dblk)
            #pragma unroll
            for (int r = 0; r < 16; ++r) st.acc[dblk][r] *= f;
        st.m_i = mnew;
    }

    float ssum = 0.f;
    #pragma unroll
    for (int g = 0; g < 2; ++g)
        #pragma unroll
        for (int r = 0; r < 16; ++r) {
            float e = __expf(sv[g][r] - st.m_i);
            sv[g][r] = e;
            ssum += e;
        }
    ssum += __shfl_xor(ssum, 32);
    st.l_i += ssum;

    unsigned w[2][4][2];
    #pragma unroll
    for (int g = 0; g < 2; ++g)
        #pragma unroll
        for (int q4 = 0; q4 < 4; ++q4) {
            w[g][q4][0] = pk2(sv[g][4 * q4 + 0], sv[g][4 * q4 + 1]);
            w[g][q4][1] = pk2(sv[g][4 * q4 + 2], sv[g][4 * q4 + 3]);
        }
    bf16x8 pfrag[4];
    #pragma unroll
    for (int ks = 0; ks < 4; ++ks) {
        int g = ks >> 1, h2 = ks & 1;
        unsigned o0 = hi ? w[g][2 * h2 + 1][0] : w[g][2 * h2][0];
        unsigned o1 = hi ? w[g][2 * h2 + 1][1] : w[g][2 * h2][1];
        unsigned t0 = hi ? w[g][2 * h2][0] : w[g][2 * h2 + 1][0];
        unsigned t1 = hi ? w[g][2 * h2][1] : w[g][2 * h2 + 1][1];
        unsigned s0v = __shfl_xor(t0, 32);
        unsigned s1v = __shfl_xor(t1, 32);
        union { unsigned u[4]; bf16x8 v; } cv;
        cv.u[0] = hi ? s0v : o0;
        cv.u[1] = hi ? s1v : o1;
        cv.u[2] = hi ? o0 : s0v;
        cv.u[3] = hi ? o1 : s1v;
        pfrag[ks] = cv.v;
    }

    __builtin_amdgcn_s_setprio(1);
    #pragma unroll
    for (int dblk = 0; dblk < 4; ++dblk) {
        int d = dblk * 32 + l31;
        #pragma unroll
        for (int ks = 0; ks < 4; ++ks) {
            if (ks >= 2 && !do_g1) continue;
            int slot = ks * 2 + hi;
            bf16x8 vf = *(const bf16x8*)(Vt + d * 64 + (slot ^ (d & 7)) * 8);
            st.acc[dblk] = MFMA32(vf, pfrag[ks], st.acc[dblk], 0, 0, 0);
        }
    }
    __builtin_amdgcn_s_setprio(0);
}

__global__ __launch_bounds__(256) void attn4_k(const u16* __restrict__ qkv,
                                               const u16* __restrict__ vt,
                                               u16* __restrict__ out) {
    const int bh = blockIdx.y;            // 0..31
    const int b = bh >> 4, h = bh & 15;
    const int j = (blockIdx.y & 16) ? (15 - blockIdx.x) : blockIdx.x;
    const int jA = j, jB = 31 - j;        // 64-row q-tile indices
    const int tid = threadIdx.x, wave = tid >> 6, lane = tid & 63;
    const int l31 = lane & 31, hi = lane >> 5;
    const int brow = b * 2048;
    __shared__ u16 Ks_lds[2][64 * 128];
    __shared__ u16 Vt_lds[2][128 * 64];

    const int krow = tid >> 4;
    const int kslot = tid & 15;
    const int vrow = tid >> 3;
    const int vslot = tid & 7;

    const int r0 = (wave < 2) ? (jA * 64 + wave * 32)
                              : (jB * 64 + (wave - 2) * 32);
    const int qg = r0 + l31;

    bf16x8 qf[8];
    {
        const u16* qp = qkv + (long)(brow + r0 + l31) * 6144 + h * 128 + hi * 8;
        #pragma unroll
        for (int dsl = 0; dsl < 8; ++dsl) qf[dsl] = *(const bf16x8*)(qp + dsl * 16);
    }

    AttnState st;
    st.m_i = -INFINITY; st.l_i = 0.f;
    #pragma unroll
    for (int dblk = 0; dblk < 4; ++dblk)
        #pragma unroll
        for (int r = 0; r < 16; ++r) st.acc[dblk][r] = 0.f;

    const int nt = jB + 1;                // kv tiles 0..jB
    int cur = 0;

#define STAGE_KV(BUF, KV0) do { \
    _Pragma("unroll") \
    for (int i = 0; i < 4; ++i) { \
        int kv = i * 16 + krow; \
        int sw = (kslot & 8) | ((kslot & 7) ^ (kv & 7)); \
        const u16* src = qkv + (long)(brow + (KV0) + kv) * 6144 + 2048 + \
                         h * 128 + sw * 8; \
        gload_lds16(src, (char*)Ks_lds[BUF] + (i * 16 + wave * 4) * 256); \
    } \
    _Pragma("unroll") \
    for (int i = 0; i < 4; ++i) { \
        int d = i * 32 + vrow; \
        int sw = vslot ^ (d & 7); \
        const u16* src = vt + ((long)bh * 128 + d) * 2048 + (KV0) + sw * 8; \
        gload_lds16(src, (char*)Vt_lds[BUF] + (i * 32 + wave * 8) * 128); \
    } \
} while (0)

    STAGE_KV(0, 0);
    for (int t = 0; t < nt; ++t) {
        const int kv0 = t * 64;
        const bool more = (t + 1 < nt);
        if (more) {
            if (cur) STAGE_KV(0, kv0 + 64); else STAGE_KV(1, kv0 + 64);
        }
        if (more) { asm volatile("s_waitcnt vmcnt(8)" ::: "memory"); }
        else      { asm volatile("s_waitcnt vmcnt(0)" ::: "memory"); }
        __builtin_amdgcn_sched_barrier(0);
        __builtin_amdgcn_s_barrier();
        __builtin_amdgcn_sched_barrier(0);
        {
            const u16* Ks = Ks_lds[cur];
            const u16* Vt_ = Vt_lds[cur];
            const int delta = r0 - kv0;
            if (delta >= 64)
                attn_tile<false>(kv0, qg, true, l31, hi, Ks, Vt_, qf, st);
            else if (delta >= 0)
                attn_tile<true>(kv0, qg, delta >= 32, l31, hi, Ks, Vt_, qf, st);
        }
        __builtin_amdgcn_sched_barrier(0);
        __builtin_amdgcn_s_barrier();
        __builtin_amdgcn_sched_barrier(0);
        cur ^= 1;
    }
#undef STAGE_KV

    float inv = 1.0f / st.l_i;
    long orow = (long)(brow + r0 + l31);
    #pragma unroll
    for (int dblk = 0; dblk < 4; ++dblk)
        #pragma unroll
        for (int rq = 0; rq < 4; ++rq) {
            u16x4 o4;
            #pragma unroll
            for (int m = 0; m < 4; ++m) o4[m] = f2b(st.acc[dblk][rq * 4 + m] * inv);
            int d = dblk * 32 + 8 * rq + 4 * hi;
            *(u16x4*)(out + orow * 2048 + h * 128 + d) = o4;
        }
}

// ---------------- launch --------------------------------------------------
extern "C" void kernel_launch(void* const* d_in, const int* in_sizes, int n_in,
                              void* d_out, int out_size, void* d_ws, size_t ws_size,
                              hipStream_t stream) {
    const float* x     = (const float*)d_in[0];
    const float* cosb  = (const float*)d_in[1];
    const float* sinb  = (const float*)d_in[2];
    const float* g1    = (const float*)d_in[3];
    const float* g2    = (const float*)d_in[4];
    const float* w_qkv = (const float*)d_in[5];
    const float* w_out = (const float*)d_in[6];
    const float* w_fc1 = (const float*)d_in[7];
    const float* w_fc2 = (const float*)d_in[8];

    char* ws = (char*)d_ws;
    u16* wqkv_b = (u16*)(ws);                    // 6144x2048 bf16
    u16* wout_b = (u16*)(ws + 25165824);         // 2048x2048
    u16* wfc1_b = (u16*)(ws + 33554432);         // 8192x2048
    u16* wfc2_b = (u16*)(ws + 67108864);         // 2048x8192
    u16* h_b    = (u16*)(ws + 100663296);        // 4096x2048 (h1 / h2)
    u16* qkv_b  = (u16*)(ws + 117440512);        // 4096x6144 (q,k; v -> vt)
    u16* attn_b = (u16*)(ws + 167772160);        // 4096x2048
    u16* hg_b   = qkv_b;                         // 4096x8192 (fc1 out)
    u16* vt_b   = (u16*)d_out;                   // 32x128x2048 bf16 (16.7MB),
                                                 // d_out dead until addrednorm
    float* p0op = (float*)d_out;                 // out-proj partial 0 (33.5MB,
                                                 // overwrites dead vt; addrednorm
                                                 // self-aliases xout==p0 per-thread)
    float* p1op = (float*)(ws + 117440512);      // out-proj partial 1 (dead qkv)
    float* part = (float*)ws;                    // fc2 partials over dead weights
    float* xout = (float*)d_out;

    // fused weight-convert + rmsnorm1 (disjoint outputs, one dispatch)
    cvtnorm_k<<<53248, 256, 0, stream>>>(w_qkv, w_out, w_fc1, w_fc2, (u16*)ws,
                                         x, g1, h_b);
    gemm256<4><<<384, 512, 0, stream>>>(h_b, wqkv_b, 4096, 6144, 2048,
                                        qkv_b, nullptr, nullptr, nullptr,
                                        vt_b, 1);
    rope_k<<<8192, 256, 0, stream>>>(qkv_b, cosb, sinb);
    attn4_k<<<dim3(16, 32), 256, 0, stream>>>(qkv_b, vt_b, attn_b);
    gemm256<3><<<256, 512, 0, stream>>>(attn_b, wout_b, 4096, 2048, 2048,
                                        nullptr, p0op, p1op, nullptr,
                                        nullptr, 2);
    addrednorm_k<<<4096, 256, 0, stream>>>(xout, x, p0op, p1op, g2, h_b);
    gemm256<2><<<512, 512, 0, stream>>>(h_b, wfc1_b, 4096, 8192, 2048,
                                        hg_b, nullptr, nullptr, nullptr,
                                        nullptr, 1);
    gemm256<3><<<256, 512, 0, stream>>>(hg_b, wfc2_b, 4096, 2048, 8192,
                                        nullptr, part, part + 8388608, nullptr,
                                        nullptr, 2);
    addred_k<<<8192, 256, 0, stream>>>(xout, part, part + 8388608);
}